// Round 2
// baseline (820.690 us; speedup 1.0000x reference)
//
#include <hip/hip_runtime.h>
#include <stdint.h>

// Problem: B=4, S=2048, E=1024, H=16, D=64. Inputs/outputs are FP32 (the
// reference's dtype; round-1 NaN was fp32 data read as bf16). Compute in bf16
// MFMA (threshold 2.5e-2 ~ 2% of ref absmax admits it), fp32 accumulate.
// Pipeline: [fused QKV proj GEMMs, f32->bf16 staging] -> [bf16 flash attn]
//           -> [output GEMM, bf16 A x f32 W -> f32 out].

typedef unsigned short u16;
typedef __bf16 bf16x8 __attribute__((ext_vector_type(8)));
typedef float f32x4 __attribute__((ext_vector_type(4)));

#define MFMA_BF16(a, b, c) __builtin_amdgcn_mfma_f32_16x16x32_bf16((a), (b), (c), 0, 0, 0)

static __device__ __forceinline__ u16 f2bf(float f) {
    uint32_t u = __builtin_bit_cast(uint32_t, f);
    u = (u + 0x7FFFu + ((u >> 16) & 1u)) >> 16;   // RNE
    return (u16)u;
}

// two fp32 -> packed bf16 pair (RNE, unbiased), pack via v_perm_b32
static __device__ __forceinline__ uint32_t pk_rne2(float a, float b) {
    uint32_t ua = __builtin_bit_cast(uint32_t, a);
    uint32_t ub = __builtin_bit_cast(uint32_t, b);
    ua += 0x7FFFu + ((ua >> 16) & 1u);
    ub += 0x7FFFu + ((ub >> 16) & 1u);
    return __builtin_amdgcn_perm(ub, ua, 0x07060302);  // [b.hi16 : a.hi16]
}

// ---------------------------------------------------------------------------
// C[m][n] = sum_p A_p[m][k] * W_p[n][k]  (A @ W^T). M=8192, N=K=1024.
// 128x128 tile, BK=32, 256 threads (4 waves, each 64x64 via 4x4 mfma
// 16x16x32 bf16). A is fp32 or bf16 per template; W always fp32; staging
// converts to bf16 in LDS. Verified layouts (learn_hip m89/m91):
//   A-frag: lane holds A[m=lane&15][k=(lane>>4)*8+j]
//   B-frag: lane holds W[n=lane&15][k=(lane>>4)*8+j]
//   C/D  : lane holds D[row=(lane>>4)*4+reg][col=lane&15]
// ---------------------------------------------------------------------------
template <bool A_F32, bool OUT_F32>
__global__ __launch_bounds__(256, 2) void gemm_bt(
    const void* __restrict__ A0v, const float* __restrict__ W0,
    const void* __restrict__ A1v, const float* __restrict__ W1,
    void* __restrict__ Cv, int N, int K, int npairs)
{
    __shared__ __align__(16) u16 lA[128 * 32];   // 8 KB (bf16 tile)
    __shared__ __align__(16) u16 lB[128 * 32];   // 8 KB

    const int tid  = threadIdx.x;
    const int lane = tid & 63;
    const int wave = tid >> 6;
    const int wm   = (wave >> 1) * 64;
    const int wn   = (wave & 1) * 64;
    const size_t m0 = (size_t)blockIdx.x * 128;
    const size_t n0 = (size_t)blockIdx.y * 128;

    const int srow = tid >> 1;          // staging row 0..127
    const int c16  = (tid & 1) * 16;    // staging col chunk (16 elements)
    const int fr   = lane & 15;
    const int g    = lane >> 4;

    f32x4 acc[4][4] = {};

    for (int p = 0; p < npairs; ++p) {
        const void*  Av = p ? A1v : A0v;
        const float* W  = p ? W1 : W0;
        for (int k0 = 0; k0 < K; k0 += 32) {
            __syncthreads();  // previous iteration's LDS readers done
            // ---- stage A tile (convert to bf16 if fp32) ----
            if (A_F32) {
                const float* src = (const float*)Av + (m0 + srow) * (size_t)K + k0 + c16;
                float4 f0 = ((const float4*)src)[0];
                float4 f1 = ((const float4*)src)[1];
                float4 f2 = ((const float4*)src)[2];
                float4 f3 = ((const float4*)src)[3];
                uint4 w0, w1;
                w0.x = pk_rne2(f0.x, f0.y); w0.y = pk_rne2(f0.z, f0.w);
                w0.z = pk_rne2(f1.x, f1.y); w0.w = pk_rne2(f1.z, f1.w);
                w1.x = pk_rne2(f2.x, f2.y); w1.y = pk_rne2(f2.z, f2.w);
                w1.z = pk_rne2(f3.x, f3.y); w1.w = pk_rne2(f3.z, f3.w);
                *(uint4*)(lA + srow * 32 + c16)     = w0;
                *(uint4*)(lA + srow * 32 + c16 + 8) = w1;
            } else {
                const u16* src = (const u16*)Av + (m0 + srow) * (size_t)K + k0 + c16;
                *(uint4*)(lA + srow * 32 + c16)     = ((const uint4*)src)[0];
                *(uint4*)(lA + srow * 32 + c16 + 8) = ((const uint4*)src)[1];
            }
            // ---- stage W tile (always fp32 -> bf16) ----
            {
                const float* src = W + (n0 + srow) * (size_t)K + k0 + c16;
                float4 f0 = ((const float4*)src)[0];
                float4 f1 = ((const float4*)src)[1];
                float4 f2 = ((const float4*)src)[2];
                float4 f3 = ((const float4*)src)[3];
                uint4 w0, w1;
                w0.x = pk_rne2(f0.x, f0.y); w0.y = pk_rne2(f0.z, f0.w);
                w0.z = pk_rne2(f1.x, f1.y); w0.w = pk_rne2(f1.z, f1.w);
                w1.x = pk_rne2(f2.x, f2.y); w1.y = pk_rne2(f2.z, f2.w);
                w1.z = pk_rne2(f3.x, f3.y); w1.w = pk_rne2(f3.z, f3.w);
                *(uint4*)(lB + srow * 32 + c16)     = w0;
                *(uint4*)(lB + srow * 32 + c16 + 8) = w1;
            }
            __syncthreads();

            bf16x8 af[4], bf[4];
#pragma unroll
            for (int i = 0; i < 4; ++i)
                af[i] = *(const bf16x8*)(lA + (wm + i * 16 + fr) * 32 + g * 8);
#pragma unroll
            for (int i = 0; i < 4; ++i)
                bf[i] = *(const bf16x8*)(lB + (wn + i * 16 + fr) * 32 + g * 8);
#pragma unroll
            for (int i = 0; i < 4; ++i)
#pragma unroll
                for (int j = 0; j < 4; ++j)
                    acc[i][j] = MFMA_BF16(af[i], bf[j], acc[i][j]);
        }
    }

#pragma unroll
    for (int i = 0; i < 4; ++i)
#pragma unroll
        for (int j = 0; j < 4; ++j)
#pragma unroll
            for (int rg = 0; rg < 4; ++rg) {
                size_t row = m0 + wm + i * 16 + g * 4 + rg;
                size_t col = n0 + wn + j * 16 + fr;
                if (OUT_F32)
                    ((float*)Cv)[row * (size_t)N + col] = acc[i][j][rg];
                else
                    ((u16*)Cv)[row * (size_t)N + col] = f2bf(acc[i][j][rg]);
            }
}

// ---------------------------------------------------------------------------
// Flash attention, non-causal, all-bf16 buffers (8192 x 1024), head h at cols
// h*64..h*64+63. Grid (16, 64), 256 threads; wave owns 32 q-rows; K-tiles of
// 128; exp2-domain online softmax. LDS strides padded +8 elems (16B) -> only
// free 2-way bank conflicts.
// ---------------------------------------------------------------------------
#define GAMMA 0.18033688011112042f   // 0.125 * log2(e)

__global__ __launch_bounds__(256, 2) void flash_kernel(
    const u16* __restrict__ Qb, const u16* __restrict__ Kb,
    const u16* __restrict__ Vb, u16* __restrict__ Ob)
{
    __shared__ __align__(16) u16 sK[128 * 72];
    __shared__ __align__(16) u16 sVt[64 * 136];
    __shared__ __align__(16) u16 sPQ[4 * 32 * 136];  // sQ(128x72) then per-wave P(32x136)

    const int tid  = threadIdx.x;
    const int lane = tid & 63;
    const int wave = tid >> 6;
    const int fr   = lane & 15;
    const int g    = lane >> 4;

    const int bh = blockIdx.y;
    const size_t rowbase = (size_t)(bh >> 4) * 2048;
    const int colbase = (bh & 15) * 64;
    const int q0 = blockIdx.x * 128;

    u16* sQ = sPQ;

#pragma unroll
    for (int pass = 0; pass < 4; ++pass) {
        int rr = pass * 32 + (tid >> 3);
        int cc = (tid & 7) * 8;
        *(uint4*)(sQ + rr * 72 + cc) =
            *(const uint4*)(Qb + (rowbase + q0 + rr) * 1024 + colbase + cc);
    }
    __syncthreads();

    bf16x8 qa[2][2];
#pragma unroll
    for (int mt = 0; mt < 2; ++mt)
#pragma unroll
        for (int kk = 0; kk < 2; ++kk)
            qa[mt][kk] = *(const bf16x8*)(sQ + (wave * 32 + mt * 16 + fr) * 72 + kk * 32 + g * 8);

    float mrow[2][4], lrow[2][4];
    f32x4 oacc[2][4] = {};
#pragma unroll
    for (int mt = 0; mt < 2; ++mt)
#pragma unroll
        for (int rg = 0; rg < 4; ++rg) { mrow[mt][rg] = -1e30f; lrow[mt][rg] = 0.f; }

    for (int kt = 0; kt < 16; ++kt) {
        __syncthreads();  // prior tile's readers done; orders sQ reads vs P writes
#pragma unroll
        for (int pass = 0; pass < 4; ++pass) {
            int rr = pass * 32 + (tid >> 3);
            int cc = (tid & 7) * 8;
            *(uint4*)(sK + rr * 72 + cc) =
                *(const uint4*)(Kb + (rowbase + kt * 128 + rr) * 1024 + colbase + cc);
        }
#pragma unroll
        for (int pass = 0; pass < 4; ++pass) {
            int key = pass * 32 + (tid >> 3);
            int d0  = (tid & 7) * 8;
            u16 tmp[8];
            *(uint4*)tmp = *(const uint4*)(Vb + (rowbase + kt * 128 + key) * 1024 + colbase + d0);
#pragma unroll
            for (int j = 0; j < 8; ++j) sVt[(d0 + j) * 136 + key] = tmp[j];
        }
        __syncthreads();

        // S(32x128) = Q(32x64) @ K^T
        f32x4 sacc[2][8] = {};
#pragma unroll
        for (int nt = 0; nt < 8; ++nt) {
            bf16x8 kb0 = *(const bf16x8*)(sK + (nt * 16 + fr) * 72 + 0 + g * 8);
            bf16x8 kb1 = *(const bf16x8*)(sK + (nt * 16 + fr) * 72 + 32 + g * 8);
            sacc[0][nt] = MFMA_BF16(qa[0][0], kb0, sacc[0][nt]);
            sacc[0][nt] = MFMA_BF16(qa[0][1], kb1, sacc[0][nt]);
            sacc[1][nt] = MFMA_BF16(qa[1][0], kb0, sacc[1][nt]);
            sacc[1][nt] = MFMA_BF16(qa[1][1], kb1, sacc[1][nt]);
        }

        // online softmax; row lives in 16 lanes sharing g
#pragma unroll
        for (int mt = 0; mt < 2; ++mt) {
#pragma unroll
            for (int rg = 0; rg < 4; ++rg) {
                float v = sacc[mt][0][rg];
#pragma unroll
                for (int nt = 1; nt < 8; ++nt) v = fmaxf(v, sacc[mt][nt][rg]);
#pragma unroll
                for (int m = 1; m < 16; m <<= 1) v = fmaxf(v, __shfl_xor(v, m, 16));
                float mnew  = fmaxf(mrow[mt][rg], GAMMA * v);
                float alpha = exp2f(mrow[mt][rg] - mnew);
                mrow[mt][rg] = mnew;
                float rs = 0.f;
#pragma unroll
                for (int nt = 0; nt < 8; ++nt) {
                    float pv = exp2f(GAMMA * sacc[mt][nt][rg] - mnew);
                    sacc[mt][nt][rg] = pv;
                    rs += pv;
                }
#pragma unroll
                for (int m = 1; m < 16; m <<= 1) rs += __shfl_xor(rs, m, 16);
                lrow[mt][rg] = lrow[mt][rg] * alpha + rs;
#pragma unroll
                for (int nt = 0; nt < 4; ++nt) oacc[mt][nt][rg] *= alpha;
            }
        }

        // P (C-layout) -> per-wave LDS in A-source order (wave-local)
        u16* sP = sPQ + wave * 32 * 136;
#pragma unroll
        for (int mt = 0; mt < 2; ++mt)
#pragma unroll
            for (int nt = 0; nt < 8; ++nt)
#pragma unroll
                for (int rg = 0; rg < 4; ++rg)
                    sP[(mt * 16 + g * 4 + rg) * 136 + nt * 16 + fr] = f2bf(sacc[mt][nt][rg]);
        // wave-local RAW through LDS with differing access types: force both
        // compiler ordering and HW drain before the A-frag reads.
        asm volatile("s_waitcnt lgkmcnt(0)" ::: "memory");

        // O(32x64) += P(32x128) @ V(128x64)
#pragma unroll
        for (int kk = 0; kk < 4; ++kk) {
            bf16x8 pa0 = *(const bf16x8*)(sP + (fr) * 136 + kk * 32 + g * 8);
            bf16x8 pa1 = *(const bf16x8*)(sP + (16 + fr) * 136 + kk * 32 + g * 8);
#pragma unroll
            for (int nt = 0; nt < 4; ++nt) {
                bf16x8 vb = *(const bf16x8*)(sVt + (nt * 16 + fr) * 136 + kk * 32 + g * 8);
                oacc[0][nt] = MFMA_BF16(pa0, vb, oacc[0][nt]);
                oacc[1][nt] = MFMA_BF16(pa1, vb, oacc[1][nt]);
            }
        }
    }

#pragma unroll
    for (int mt = 0; mt < 2; ++mt)
#pragma unroll
        for (int rg = 0; rg < 4; ++rg) {
            float inv = 1.0f / lrow[mt][rg];
            size_t row = rowbase + q0 + wave * 32 + mt * 16 + g * 4 + rg;
#pragma unroll
            for (int nt = 0; nt < 4; ++nt)
                Ob[row * 1024 + colbase + nt * 16 + fr] = f2bf(oacc[mt][nt][rg] * inv);
        }
}

// ---------------------------------------------------------------------------
extern "C" void kernel_launch(void* const* d_in, const int* in_sizes, int n_in,
                              void* d_out, int out_size, void* d_ws, size_t ws_size,
                              hipStream_t stream)
{
    const float* X    = (const float*)d_in[0];
    const float* R    = (const float*)d_in[1];
    const float* E    = (const float*)d_in[2];
    const float* Wq   = (const float*)d_in[3];
    const float* Wk   = (const float*)d_in[4];
    const float* Wv   = (const float*)d_in[5];
    const float* Wrot = (const float*)d_in[6];
    const float* Went = (const float*)d_in[7];
    const float* Wo   = (const float*)d_in[8];

    const size_t NTOK = 8192, EMB = 1024;
    u16* Qb = (u16*)d_ws;                 // bf16 intermediates: 4 x 16.78 MB
    u16* Kb = Qb + NTOK * EMB;
    u16* Vb = Kb + NTOK * EMB;
    u16* Ob = Vb + NTOK * EMB;

    dim3 gproj(8192 / 128, 1024 / 128);   // (64, 8)
    gemm_bt<true,  false><<<gproj, 256, 0, stream>>>(X,  Wq, R, Wrot, Qb, 1024, 1024, 2);
    gemm_bt<true,  false><<<gproj, 256, 0, stream>>>(X,  Wk, E, Went, Kb, 1024, 1024, 2);
    gemm_bt<true,  false><<<gproj, 256, 0, stream>>>(X,  Wv, nullptr, nullptr, Vb, 1024, 1024, 1);
    flash_kernel<<<dim3(16, 64), 256, 0, stream>>>(Qb, Kb, Vb, Ob);
    gemm_bt<false, true ><<<gproj, 256, 0, stream>>>(Ob, Wo, nullptr, nullptr, d_out, 1024, 1024, 1);
}

// Round 3
// 755.964 us; speedup vs baseline: 1.0856x; 1.0856x over previous
//
#include <hip/hip_runtime.h>
#include <stdint.h>

// B=4, S=2048, E=1024, H=16, D=64. fp32 I/O; bf16 MFMA compute.
// Pipeline: [cvt fp32->bf16 once] -> [pure-bf16 proj GEMMs w/ global_load_lds]
//           -> [swizzled flash attn, constant-max softmax] -> [out GEMM fp32].
// Scratch: Qb/Kb live in d_out (re-poisoned by harness, overwritten at end);
// ws holds Xb, Rb/Vb, Eb/Ob, 6 bf16 weights = 62.9 MB (<= 67 MB proven).

typedef unsigned short u16;
typedef __bf16 bf16x8 __attribute__((ext_vector_type(8)));
typedef float f32x4 __attribute__((ext_vector_type(4)));

#define MFMA_BF16(a, b, c) __builtin_amdgcn_mfma_f32_16x16x32_bf16((a), (b), (c), 0, 0, 0)
#define GAMMA 0.18033688011112042f   // (1/8) * log2(e): folded into Q projection

static __device__ __forceinline__ u16 f2bf(float f) {
    uint32_t u = __builtin_bit_cast(uint32_t, f);
    u = (u + 0x7FFFu + ((u >> 16) & 1u)) >> 16;   // RNE
    return (u16)u;
}

static __device__ __forceinline__ uint32_t pk_rne2(float a, float b) {
    uint32_t ua = __builtin_bit_cast(uint32_t, a);
    uint32_t ub = __builtin_bit_cast(uint32_t, b);
    ua += 0x7FFFu + ((ua >> 16) & 1u);
    ub += 0x7FFFu + ((ub >> 16) & 1u);
    return __builtin_amdgcn_perm(ub, ua, 0x07060302);
}

static __device__ __forceinline__ void async_copy16(const void* g, void* l) {
    __builtin_amdgcn_global_load_lds((__attribute__((address_space(1))) void*)g,
                                     (__attribute__((address_space(3))) void*)l,
                                     16, 0, 0);
}

// ---------------------------------------------------------------------------
// fp32 -> bf16 batched converter. grid.z selects tensor; grid.x*256*8 == nelem.
// ---------------------------------------------------------------------------
struct CvtArgs { const float* s[6]; u16* d[6]; };

__global__ __launch_bounds__(256) void cvt_kernel(CvtArgs a, int nelem) {
    const float* s = a.s[blockIdx.z];
    u16* d = a.d[blockIdx.z];
    int i = (blockIdx.x * 256 + threadIdx.x) * 8;
    float4 f0 = *(const float4*)(s + i);
    float4 f1 = *(const float4*)(s + i + 4);
    uint4 w;
    w.x = pk_rne2(f0.x, f0.y); w.y = pk_rne2(f0.z, f0.w);
    w.z = pk_rne2(f1.x, f1.y); w.w = pk_rne2(f1.z, f1.w);
    *(uint4*)(d + i) = w;
}

// ---------------------------------------------------------------------------
// C = scale * sum_p A_p @ W_p^T, all bf16 row-major (W is (N,K)). M=8192,
// N=K=1024. 128x128 tile, BK=32, 4 waves @ 64x64, async global->LDS staging.
// Layouts verified (m89/m91 + round-2 pass with identical indexing).
// ---------------------------------------------------------------------------
template <bool OUT_F32>
__global__ __launch_bounds__(256, 2) void gemm_bt(
    const u16* __restrict__ A0, const u16* __restrict__ W0,
    const u16* __restrict__ A1, const u16* __restrict__ W1,
    void* __restrict__ Cv, int N, int K, int npairs, float scale)
{
    __shared__ __align__(16) u16 lA[128 * 32];
    __shared__ __align__(16) u16 lB[128 * 32];

    const int tid  = threadIdx.x;
    const int lane = tid & 63;
    const int wave = tid >> 6;
    const int wm   = (wave >> 1) * 64;
    const int wn   = (wave & 1) * 64;
    const size_t m0 = (size_t)blockIdx.x * 128;
    const size_t n0 = (size_t)blockIdx.y * 128;

    const int r  = tid >> 2;
    const int c8 = (tid & 3) * 8;
    const int fr = lane & 15;
    const int g  = lane >> 4;

    f32x4 acc[4][4] = {};

    for (int p = 0; p < npairs; ++p) {
        const u16* A = p ? A1 : A0;
        const u16* W = p ? W1 : W0;
        for (int k0 = 0; k0 < K; k0 += 32) {
            __syncthreads();
            async_copy16(A + ((m0 + r) * (size_t)K + k0 + c8),      lA + tid * 8);
            async_copy16(A + ((m0 + r + 64) * (size_t)K + k0 + c8), lA + 2048 + tid * 8);
            async_copy16(W + ((n0 + r) * (size_t)K + k0 + c8),      lB + tid * 8);
            async_copy16(W + ((n0 + r + 64) * (size_t)K + k0 + c8), lB + 2048 + tid * 8);
            __syncthreads();

            bf16x8 af[4], bf[4];
#pragma unroll
            for (int i = 0; i < 4; ++i)
                af[i] = *(const bf16x8*)(lA + (wm + i * 16 + fr) * 32 + g * 8);
#pragma unroll
            for (int i = 0; i < 4; ++i)
                bf[i] = *(const bf16x8*)(lB + (wn + i * 16 + fr) * 32 + g * 8);
#pragma unroll
            for (int i = 0; i < 4; ++i)
#pragma unroll
                for (int j = 0; j < 4; ++j)
                    acc[i][j] = MFMA_BF16(af[i], bf[j], acc[i][j]);
        }
    }

#pragma unroll
    for (int i = 0; i < 4; ++i)
#pragma unroll
        for (int j = 0; j < 4; ++j)
#pragma unroll
            for (int rg = 0; rg < 4; ++rg) {
                size_t row = m0 + wm + i * 16 + g * 4 + rg;
                size_t col = n0 + wn + j * 16 + fr;
                float v = acc[i][j][rg] * scale;
                if (OUT_F32) ((float*)Cv)[row * (size_t)N + col] = v;
                else         ((u16*)Cv)[row * (size_t)N + col] = f2bf(v);
            }
}

// ---------------------------------------------------------------------------
// Flash attention, non-causal, bf16 buffers (8192x1024), head h at cols
// h*64..+63. Grid (16,64), 256 threads; wave owns 32 q-rows; 128-key tiles.
// Constant-max softmax (scores |gamma*s| << 127: shift-invariant, fp32-safe).
// XOR swizzle swz(row)=((row>>3)^row)&7 on 8-elem chunks: V-scatter
// conflict-free, all b128 reads at the 8-access/bank minimum, and Q/K can
// stage via global_load_lds (no padding). LDS 42 KB -> 3 blocks/CU.
// ---------------------------------------------------------------------------
__global__ __launch_bounds__(256, 3) void flash_kernel(
    const u16* __restrict__ Qb, const u16* __restrict__ Kb,
    const u16* __restrict__ Vb, u16* __restrict__ Ob)
{
    __shared__ __align__(16) u16 sK[128 * 64];     // swizzled; aliases sQ at start
    __shared__ __align__(16) u16 sVt[64 * 128];    // V^T, key-chunk swizzled
    __shared__ __align__(16) u16 sP[4][32 * 40];   // per-wave P chunk (32q x 32k)

    const int tid  = threadIdx.x;
    const int lane = tid & 63;
    const int wave = tid >> 6;
    const int fr   = lane & 15;
    const int g    = lane >> 4;

    const int bh = blockIdx.y;
    const size_t rowbase = (size_t)(bh >> 4) * 2048;
    const int colbase = (bh & 15) * 64;
    const int q0 = blockIdx.x * 128;

    // ---- stage Q (async, swizzled) into sK region ----
    {
        const int r8 = tid >> 3, cpos = tid & 7;
#pragma unroll
        for (int pass = 0; pass < 4; ++pass) {
            int row = pass * 32 + r8;
            int sc = cpos ^ (((row >> 3) ^ row) & 7);
            async_copy16(Qb + (rowbase + q0 + row) * 1024 + colbase + sc * 8,
                         (char*)sK + pass * 4096 + tid * 16);
        }
    }
    __syncthreads();

    bf16x8 qa[2][2];
#pragma unroll
    for (int mt = 0; mt < 2; ++mt)
#pragma unroll
        for (int c = 0; c < 2; ++c) {
            int row = wave * 32 + mt * 16 + fr;
            int sw = ((row >> 3) ^ row) & 7;
            qa[mt][c] = *(const bf16x8*)(sK + row * 64 + ((c * 4 + g) ^ sw) * 8);
        }

    f32x4 oacc[2][4] = {};
    float lsum[2][4] = {};

    for (int kt = 0; kt < 16; ++kt) {
        __syncthreads();   // prior readers of sK/sVt done (incl. qa at kt=0)
        // ---- K async, swizzled ----
        {
            const int r8 = tid >> 3, cpos = tid & 7;
#pragma unroll
            for (int pass = 0; pass < 4; ++pass) {
                int row = pass * 32 + r8;
                int sc = cpos ^ (((row >> 3) ^ row) & 7);
                async_copy16(Kb + (rowbase + kt * 128 + row) * 1024 + colbase + sc * 8,
                             (char*)sK + pass * 4096 + tid * 16);
            }
        }
        // ---- V scatter-transpose, swizzled (conflict-free) ----
        {
            const int d8 = tid & 7;
            const int k8 = (tid >> 3) & 7;
#pragma unroll
            for (int pass = 0; pass < 4; ++pass) {
                int key = pass * 32 + (tid >> 3);
                int kb = pass * 4 + wave;
                u16 tmp[8];
                *(uint4*)tmp = *(const uint4*)(Vb + (rowbase + kt * 128 + key) * 1024 + colbase + d8 * 8);
#pragma unroll
                for (int j = 0; j < 8; ++j) {
                    int d = d8 * 8 + j;
                    int pos = kb ^ (d8 ^ j);          // swzV(d) = ((d>>3)^d)&7 = d8^j
                    sVt[d * 128 + pos * 8 + k8] = tmp[j];
                }
            }
        }
        __syncthreads();

        // ---- scores: S(32x128) = (gamma Q)(32x64) @ K^T ----
        f32x4 sacc[2][8] = {};
#pragma unroll
        for (int nt = 0; nt < 8; ++nt) {
            int row = nt * 16 + fr;
            int sw = ((row >> 3) ^ row) & 7;
            bf16x8 kb0 = *(const bf16x8*)(sK + row * 64 + ((g) ^ sw) * 8);
            bf16x8 kb1 = *(const bf16x8*)(sK + row * 64 + ((4 + g) ^ sw) * 8);
            sacc[0][nt] = MFMA_BF16(qa[0][0], kb0, sacc[0][nt]);
            sacc[0][nt] = MFMA_BF16(qa[0][1], kb1, sacc[0][nt]);
            sacc[1][nt] = MFMA_BF16(qa[1][0], kb0, sacc[1][nt]);
            sacc[1][nt] = MFMA_BF16(qa[1][1], kb1, sacc[1][nt]);
        }

        // ---- exp + PV, chunked by 32 keys ----
        u16* sPw = sP[wave];
#pragma unroll
        for (int kk = 0; kk < 4; ++kk) {
#pragma unroll
            for (int mt = 0; mt < 2; ++mt)
#pragma unroll
                for (int l = 0; l < 2; ++l) {
                    int nt = kk * 2 + l;
#pragma unroll
                    for (int rg = 0; rg < 4; ++rg) {
                        float p = exp2f(sacc[mt][nt][rg]);
                        lsum[mt][rg] += p;
                        uint32_t ub = __builtin_bit_cast(uint32_t, p) + 0x8000u;  // round-half-up
                        sPw[(mt * 16 + g * 4 + rg) * 40 + l * 16 + fr] = (u16)(ub >> 16);
                    }
                }
            asm volatile("s_waitcnt lgkmcnt(0)" ::: "memory");  // wave-local P RAW
            bf16x8 pa0 = *(const bf16x8*)(sPw + fr * 40 + g * 8);
            bf16x8 pa1 = *(const bf16x8*)(sPw + (16 + fr) * 40 + g * 8);
#pragma unroll
            for (int nt2 = 0; nt2 < 4; ++nt2) {
                int d = nt2 * 16 + fr;
                int sw = ((d >> 3) ^ d) & 7;
                bf16x8 vb = *(const bf16x8*)(sVt + d * 128 + ((kk * 4 + g) ^ sw) * 8);
                oacc[0][nt2] = MFMA_BF16(pa0, vb, oacc[0][nt2]);
                oacc[1][nt2] = MFMA_BF16(pa1, vb, oacc[1][nt2]);
            }
        }
    }

    // ---- epilogue: reduce l across the 16 lanes of each row-group, write O ----
#pragma unroll
    for (int mt = 0; mt < 2; ++mt)
#pragma unroll
        for (int rg = 0; rg < 4; ++rg) {
            float l = lsum[mt][rg];
#pragma unroll
            for (int m = 1; m < 16; m <<= 1) l += __shfl_xor(l, m, 16);
            float inv = 1.0f / l;
            size_t row = rowbase + q0 + wave * 32 + mt * 16 + g * 4 + rg;
#pragma unroll
            for (int nt = 0; nt < 4; ++nt)
                Ob[row * 1024 + colbase + nt * 16 + fr] = f2bf(oacc[mt][nt][rg] * inv);
        }
}

// ---------------------------------------------------------------------------
extern "C" void kernel_launch(void* const* d_in, const int* in_sizes, int n_in,
                              void* d_out, int out_size, void* d_ws, size_t ws_size,
                              hipStream_t stream)
{
    const float* X    = (const float*)d_in[0];
    const float* R    = (const float*)d_in[1];
    const float* E    = (const float*)d_in[2];
    const float* Wq   = (const float*)d_in[3];
    const float* Wk   = (const float*)d_in[4];
    const float* Wv   = (const float*)d_in[5];
    const float* Wrot = (const float*)d_in[6];
    const float* Went = (const float*)d_in[7];
    const float* Wo   = (const float*)d_in[8];

    const size_t NT = 8192 * 1024;      // activation elems
    const size_t NW = 1024 * 1024;      // weight elems

    // d_out doubles as scratch for Qb/Kb (bf16), overwritten by final fp32 GEMM.
    u16* Qb  = (u16*)d_out;
    u16* Kb  = Qb + NT;
    // ws: Xb | Rb->Vb | Eb->Ob | 6 bf16 weights  (62.9 MB)
    u16* Xb  = (u16*)d_ws;
    u16* RVb = Xb + NT;
    u16* EOb = RVb + NT;
    u16* Wqb = EOb + NT;
    u16* Wkb   = Wqb + NW;
    u16* Wvb   = Wkb + NW;
    u16* Wrotb = Wvb + NW;
    u16* Wentb = Wrotb + NW;
    u16* Wob   = Wentb + NW;

    {   // activations: 3 x 8.39M elems, 4096*256*8 == 8388608
        CvtArgs a{};
        a.s[0] = X; a.s[1] = R; a.s[2] = E;
        a.d[0] = Xb; a.d[1] = RVb; a.d[2] = EOb;
        cvt_kernel<<<dim3(4096, 1, 3), 256, 0, stream>>>(a, (int)NT);
    }
    {   // weights: 6 x 1.05M elems, 512*256*8 == 1048576
        CvtArgs a{};
        a.s[0] = Wq; a.s[1] = Wk; a.s[2] = Wv; a.s[3] = Wrot; a.s[4] = Went; a.s[5] = Wo;
        a.d[0] = Wqb; a.d[1] = Wkb; a.d[2] = Wvb; a.d[3] = Wrotb; a.d[4] = Wentb; a.d[5] = Wob;
        cvt_kernel<<<dim3(512, 1, 6), 256, 0, stream>>>(a, (int)NW);
    }

    dim3 gproj(64, 8);
    gemm_bt<false><<<gproj, 256, 0, stream>>>(Xb, Wqb, RVb, Wrotb, Qb, 1024, 1024, 2, GAMMA);
    gemm_bt<false><<<gproj, 256, 0, stream>>>(Xb, Wkb, EOb, Wentb, Kb, 1024, 1024, 2, 1.0f);
    gemm_bt<false><<<gproj, 256, 0, stream>>>(Xb, Wvb, nullptr, nullptr, RVb, 1024, 1024, 1, 1.0f);
    flash_kernel<<<dim3(16, 64), 256, 0, stream>>>(Qb, Kb, RVb, EOb);
    gemm_bt<true ><<<gproj, 256, 0, stream>>>(EOb, Wob, nullptr, nullptr, d_out, 1024, 1024, 1, 1.0f);
}

// Round 4
// 453.429 us; speedup vs baseline: 1.8100x; 1.6672x over previous
//
#include <hip/hip_runtime.h>
#include <stdint.h>

// B=4, S=2048, E=1024, H=16, D=64. fp32 I/O; bf16 MFMA compute.
// R4: head-major intermediates (Q,K=[bh][s][64], V stored transposed
// [bh][d][s], O=[bh][s][64]) + XCD-pinned flash grid so each XCD's K/V
// working set (8 bh x 512 KB = 4 MB) is L2-resident. Flash stages K and Vt
// via global_load_lds (no in-kernel transpose).
// Scratch: Qhm/Khm in d_out (33.5 MB, overwritten by final fp32 GEMM);
// ws: Xb | R->Vt | E->Ohm | 6 bf16 weights = 62.9 MB.

typedef unsigned short u16;
typedef __bf16 bf16x8 __attribute__((ext_vector_type(8)));
typedef float f32x4 __attribute__((ext_vector_type(4)));

#define MFMA_BF16(a, b, c) __builtin_amdgcn_mfma_f32_16x16x32_bf16((a), (b), (c), 0, 0, 0)
#define GAMMA 0.18033688011112042f   // (1/8) * log2(e): folded into Q projection
#define BHSTRIDE 131072              // 2048 * 64 elems per (b,h) slice

static __device__ __forceinline__ u16 f2bf(float f) {
    uint32_t u = __builtin_bit_cast(uint32_t, f);
    u = (u + 0x7FFFu + ((u >> 16) & 1u)) >> 16;   // RNE
    return (u16)u;
}

static __device__ __forceinline__ uint32_t pk_rne2(float a, float b) {
    uint32_t ua = __builtin_bit_cast(uint32_t, a);
    uint32_t ub = __builtin_bit_cast(uint32_t, b);
    ua += 0x7FFFu + ((ua >> 16) & 1u);
    ub += 0x7FFFu + ((ub >> 16) & 1u);
    return __builtin_amdgcn_perm(ub, ua, 0x07060302);
}

static __device__ __forceinline__ void async_copy16(const void* g, void* l) {
    __builtin_amdgcn_global_load_lds((__attribute__((address_space(1))) void*)g,
                                     (__attribute__((address_space(3))) void*)l,
                                     16, 0, 0);
}

// ---------------------------------------------------------------------------
// fp32 -> bf16 batched converter.
// ---------------------------------------------------------------------------
struct CvtArgs { const float* s[6]; u16* d[6]; };

__global__ __launch_bounds__(256) void cvt_kernel(CvtArgs a, int nelem) {
    const float* s = a.s[blockIdx.z];
    u16* d = a.d[blockIdx.z];
    int i = (blockIdx.x * 256 + threadIdx.x) * 8;
    float4 f0 = *(const float4*)(s + i);
    float4 f1 = *(const float4*)(s + i + 4);
    uint4 w;
    w.x = pk_rne2(f0.x, f0.y); w.y = pk_rne2(f0.z, f0.w);
    w.z = pk_rne2(f1.x, f1.y); w.w = pk_rne2(f1.z, f1.w);
    *(uint4*)(d + i) = w;
}

// ---------------------------------------------------------------------------
// C = scale * sum_p A_p @ W_p^T, bf16, M=8192, N=K=1024, 128x128 tile, BK=32.
// AMODE: 0 = A natural row-major (M x K); 1 = A head-major [bh][s][64].
// CMODE: 0 = fp32 natural; 1 = bf16 head-major [bh][s][64];
//        2 = bf16 transposed head-major [bh][d][s] (packed 4-token stores).
// ---------------------------------------------------------------------------
template <int AMODE, int CMODE>
__global__ __launch_bounds__(256, 2) void gemm_bt(
    const u16* __restrict__ A0, const u16* __restrict__ W0,
    const u16* __restrict__ A1, const u16* __restrict__ W1,
    void* __restrict__ Cv, int K, int npairs, float scale)
{
    __shared__ __align__(16) u16 lA[128 * 32];
    __shared__ __align__(16) u16 lB[128 * 32];

    const int tid  = threadIdx.x;
    const int lane = tid & 63;
    const int wave = tid >> 6;
    const int wm   = (wave >> 1) * 64;
    const int wn   = (wave & 1) * 64;
    const size_t m0 = (size_t)blockIdx.x * 128;
    const size_t n0 = (size_t)blockIdx.y * 128;

    const int r  = tid >> 2;
    const int c8 = (tid & 3) * 8;
    const int fr = lane & 15;
    const int g  = lane >> 4;

    const size_t bb = (m0 >> 11) * 16;   // b*16 (tile never straddles a batch)
    const size_t s0 = m0 & 2047;

    f32x4 acc[4][4] = {};

    for (int p = 0; p < npairs; ++p) {
        const u16* A = p ? A1 : A0;
        const u16* W = p ? W1 : W0;
        for (int k0 = 0; k0 < K; k0 += 32) {
            __syncthreads();
            if (AMODE == 0) {
                async_copy16(A + ((m0 + r) * (size_t)K + k0 + c8),      lA + tid * 8);
                async_copy16(A + ((m0 + r + 64) * (size_t)K + k0 + c8), lA + 2048 + tid * 8);
            } else {
                int ch = k0 + c8;                      // 8-chunk stays in one head
                size_t base = (bb + (size_t)(ch >> 6)) * BHSTRIDE + (ch & 63);
                async_copy16(A + base + (s0 + r) * 64,      lA + tid * 8);
                async_copy16(A + base + (s0 + r + 64) * 64, lA + 2048 + tid * 8);
            }
            async_copy16(W + ((n0 + r) * (size_t)K + k0 + c8),      lB + tid * 8);
            async_copy16(W + ((n0 + r + 64) * (size_t)K + k0 + c8), lB + 2048 + tid * 8);
            __syncthreads();

            bf16x8 af[4], bf[4];
#pragma unroll
            for (int i = 0; i < 4; ++i)
                af[i] = *(const bf16x8*)(lA + (wm + i * 16 + fr) * 32 + g * 8);
#pragma unroll
            for (int i = 0; i < 4; ++i)
                bf[i] = *(const bf16x8*)(lB + (wn + i * 16 + fr) * 32 + g * 8);
#pragma unroll
            for (int i = 0; i < 4; ++i)
#pragma unroll
                for (int j = 0; j < 4; ++j)
                    acc[i][j] = MFMA_BF16(af[i], bf[j], acc[i][j]);
        }
    }

#pragma unroll
    for (int i = 0; i < 4; ++i)
#pragma unroll
        for (int j = 0; j < 4; ++j) {
            if (CMODE == 2) {
                size_t row0 = m0 + wm + i * 16 + g * 4;        // 4 consecutive tokens
                size_t col  = n0 + wn + j * 16 + fr;
                size_t addr = ((row0 >> 11) * 16 + (col >> 6)) * BHSTRIDE
                            + (size_t)(col & 63) * 2048 + (row0 & 2047);
                ushort4 pk;
                pk.x = f2bf(acc[i][j][0] * scale);
                pk.y = f2bf(acc[i][j][1] * scale);
                pk.z = f2bf(acc[i][j][2] * scale);
                pk.w = f2bf(acc[i][j][3] * scale);
                *(ushort4*)((u16*)Cv + addr) = pk;
            } else {
#pragma unroll
                for (int rg = 0; rg < 4; ++rg) {
                    size_t row = m0 + wm + i * 16 + g * 4 + rg;
                    size_t col = n0 + wn + j * 16 + fr;
                    float v = acc[i][j][rg] * scale;
                    if (CMODE == 0) {
                        ((float*)Cv)[row * 1024 + col] = v;
                    } else {
                        size_t addr = ((row >> 11) * 16 + (col >> 6)) * BHSTRIDE
                                    + (row & 2047) * 64 + (col & 63);
                        ((u16*)Cv)[addr] = f2bf(v);
                    }
                }
            }
        }
}

// ---------------------------------------------------------------------------
// Flash attention, non-causal. Head-major buffers: Q,K,O = [bh][s][64],
// Vt = [bh][d][s]. Grid 1024 linear, XCD-pinned: xcd=id&7, 8 bh per XCD ->
// per-XCD K/V working set 4 MB = L2. 256 threads, wave owns 32 q-rows,
// 128-key tiles, constant-max exp2 softmax (gamma folded into Q projection).
// sK swizzle: chunk8 ^ ((row>>3)^row)&7. sVt swizzle: chunk16 ^ (d&15).
// ---------------------------------------------------------------------------
__global__ __launch_bounds__(256, 3) void flash_kernel(
    const u16* __restrict__ Qhm, const u16* __restrict__ Khm,
    const u16* __restrict__ Vt, u16* __restrict__ Ohm)
{
    __shared__ __align__(16) u16 sK[128 * 64];     // 16 KB; aliases Q at start
    __shared__ __align__(16) u16 sVt[64 * 128];    // 16 KB
    __shared__ __align__(16) u16 sP[4][32 * 40];   // 10 KB

    const int tid  = threadIdx.x;
    const int lane = tid & 63;
    const int wave = tid >> 6;
    const int fr   = lane & 15;
    const int g    = lane >> 4;

    const int lin  = blockIdx.x;
    const int slot = lin >> 3;
    const int bh   = (lin & 7) + 8 * (slot >> 4);
    const int q0   = (slot & 15) * 128;

    const u16* Qh = Qhm + (size_t)bh * BHSTRIDE;
    const u16* Kh = Khm + (size_t)bh * BHSTRIDE;
    const u16* Vh = Vt  + (size_t)bh * BHSTRIDE;
    u16*       Oh = Ohm + (size_t)bh * BHSTRIDE;

    // ---- stage Q (async, swizzled) into sK region ----
    {
        const int row8 = tid >> 3, cpos = tid & 7;
#pragma unroll
        for (int it = 0; it < 4; ++it) {
            int row = it * 32 + row8;
            int sc = cpos ^ (((row >> 3) ^ row) & 7);
            async_copy16(Qh + (size_t)(q0 + row) * 64 + sc * 8,
                         (char*)sK + it * 4096 + tid * 16);
        }
    }
    __syncthreads();

    bf16x8 qa[2][2];
#pragma unroll
    for (int mt = 0; mt < 2; ++mt)
#pragma unroll
        for (int c = 0; c < 2; ++c) {
            int row = wave * 32 + mt * 16 + fr;
            int sw = ((row >> 3) ^ row) & 7;
            qa[mt][c] = *(const bf16x8*)(sK + row * 64 + ((c * 4 + g) ^ sw) * 8);
        }

    f32x4 oacc[2][4] = {};
    float lsum[2][4] = {};

    for (int kt = 0; kt < 16; ++kt) {
        __syncthreads();   // prior readers of sK/sVt done (incl. qa at kt=0)
        {   // K tile: 128 keys x 64 d, contiguous
            const int row8 = tid >> 3, cpos = tid & 7;
#pragma unroll
            for (int it = 0; it < 4; ++it) {
                int row = it * 32 + row8;
                int sc = cpos ^ (((row >> 3) ^ row) & 7);
                async_copy16(Kh + (size_t)(kt * 128 + row) * 64 + sc * 8,
                             (char*)sK + it * 4096 + tid * 16);
            }
        }
        {   // Vt tile: 64 d x 128 keys, contiguous per d-row
            const int d16 = tid >> 4, cpos = tid & 15;
#pragma unroll
            for (int it = 0; it < 4; ++it) {
                int d = it * 16 + d16;
                int sc = cpos ^ (d & 15);
                async_copy16(Vh + (size_t)d * 2048 + kt * 128 + sc * 8,
                             (char*)sVt + it * 4096 + tid * 16);
            }
        }
        __syncthreads();

        // ---- scores: S(32x128) = (gamma Q)(32x64) @ K^T ----
        f32x4 sacc[2][8] = {};
#pragma unroll
        for (int nt = 0; nt < 8; ++nt) {
            int row = nt * 16 + fr;
            int sw = ((row >> 3) ^ row) & 7;
            bf16x8 kb0 = *(const bf16x8*)(sK + row * 64 + ((g) ^ sw) * 8);
            bf16x8 kb1 = *(const bf16x8*)(sK + row * 64 + ((4 + g) ^ sw) * 8);
            sacc[0][nt] = MFMA_BF16(qa[0][0], kb0, sacc[0][nt]);
            sacc[0][nt] = MFMA_BF16(qa[0][1], kb1, sacc[0][nt]);
            sacc[1][nt] = MFMA_BF16(qa[1][0], kb0, sacc[1][nt]);
            sacc[1][nt] = MFMA_BF16(qa[1][1], kb1, sacc[1][nt]);
        }

        // ---- exp + PV, chunked by 32 keys ----
        u16* sPw = sP[wave];
#pragma unroll
        for (int kk = 0; kk < 4; ++kk) {
#pragma unroll
            for (int mt = 0; mt < 2; ++mt)
#pragma unroll
                for (int l = 0; l < 2; ++l) {
                    int nt = kk * 2 + l;
#pragma unroll
                    for (int rg = 0; rg < 4; ++rg) {
                        float p = exp2f(sacc[mt][nt][rg]);
                        lsum[mt][rg] += p;
                        uint32_t ub = __builtin_bit_cast(uint32_t, p) + 0x8000u;
                        sPw[(mt * 16 + g * 4 + rg) * 40 + l * 16 + fr] = (u16)(ub >> 16);
                    }
                }
            asm volatile("s_waitcnt lgkmcnt(0)" ::: "memory");  // wave-local P RAW
            bf16x8 pa0 = *(const bf16x8*)(sPw + fr * 40 + g * 8);
            bf16x8 pa1 = *(const bf16x8*)(sPw + (16 + fr) * 40 + g * 8);
#pragma unroll
            for (int nt2 = 0; nt2 < 4; ++nt2) {
                int d = nt2 * 16 + fr;
                bf16x8 vb = *(const bf16x8*)(sVt + d * 128 + ((kk * 4 + g) ^ (d & 15)) * 8);
                oacc[0][nt2] = MFMA_BF16(pa0, vb, oacc[0][nt2]);
                oacc[1][nt2] = MFMA_BF16(pa1, vb, oacc[1][nt2]);
            }
        }
    }

    // ---- epilogue ----
#pragma unroll
    for (int mt = 0; mt < 2; ++mt)
#pragma unroll
        for (int rg = 0; rg < 4; ++rg) {
            float l = lsum[mt][rg];
#pragma unroll
            for (int m = 1; m < 16; m <<= 1) l += __shfl_xor(l, m, 16);
            float inv = 1.0f / l;
            size_t row = (size_t)q0 + wave * 32 + mt * 16 + g * 4 + rg;
#pragma unroll
            for (int nt = 0; nt < 4; ++nt)
                Oh[row * 64 + nt * 16 + fr] = f2bf(oacc[mt][nt][rg] * inv);
        }
}

// ---------------------------------------------------------------------------
extern "C" void kernel_launch(void* const* d_in, const int* in_sizes, int n_in,
                              void* d_out, int out_size, void* d_ws, size_t ws_size,
                              hipStream_t stream)
{
    const float* X    = (const float*)d_in[0];
    const float* R    = (const float*)d_in[1];
    const float* E    = (const float*)d_in[2];
    const float* Wq   = (const float*)d_in[3];
    const float* Wk   = (const float*)d_in[4];
    const float* Wv   = (const float*)d_in[5];
    const float* Wrot = (const float*)d_in[6];
    const float* Went = (const float*)d_in[7];
    const float* Wo   = (const float*)d_in[8];

    const size_t NT = 8192 * 1024;
    const size_t NW = 1024 * 1024;

    // d_out doubles as scratch for Qhm/Khm (bf16, head-major).
    u16* Qhm = (u16*)d_out;
    u16* Khm = Qhm + NT;
    // ws: Xb | Rb->Vt | Eb->Ohm | 6 bf16 weights
    u16* Xb  = (u16*)d_ws;
    u16* RVb = Xb + NT;    // rotation bf16, then V^T head-major
    u16* EOb = RVb + NT;   // entangle bf16, then O head-major
    u16* Wqb = EOb + NT;
    u16* Wkb   = Wqb + NW;
    u16* Wvb   = Wkb + NW;
    u16* Wrotb = Wvb + NW;
    u16* Wentb = Wrotb + NW;
    u16* Wob   = Wentb + NW;

    {   // activations
        CvtArgs a{};
        a.s[0] = X; a.s[1] = R; a.s[2] = E;
        a.d[0] = Xb; a.d[1] = RVb; a.d[2] = EOb;
        cvt_kernel<<<dim3(4096, 1, 3), 256, 0, stream>>>(a, (int)NT);
    }
    {   // weights
        CvtArgs a{};
        a.s[0] = Wq; a.s[1] = Wk; a.s[2] = Wv; a.s[3] = Wrot; a.s[4] = Went; a.s[5] = Wo;
        a.d[0] = Wqb; a.d[1] = Wkb; a.d[2] = Wvb; a.d[3] = Wrotb; a.d[4] = Wentb; a.d[5] = Wob;
        cvt_kernel<<<dim3(512, 1, 6), 256, 0, stream>>>(a, (int)NW);
    }

    dim3 gproj(64, 8);
    gemm_bt<0, 1><<<gproj, 256, 0, stream>>>(Xb, Wqb, RVb, Wrotb, Qhm, 1024, 2, GAMMA);
    gemm_bt<0, 1><<<gproj, 256, 0, stream>>>(Xb, Wkb, EOb, Wentb, Khm, 1024, 2, 1.0f);
    gemm_bt<0, 2><<<gproj, 256, 0, stream>>>(Xb, Wvb, nullptr, nullptr, RVb, 1024, 1, 1.0f);
    flash_kernel<<<dim3(1024), 256, 0, stream>>>(Qhm, Khm, RVb, EOb);
    gemm_bt<1, 0><<<gproj, 256, 0, stream>>>(EOb, Wob, nullptr, nullptr, d_out, 1024, 1, 1.0f);
}